// Round 6
// baseline (89.598 us; speedup 1.0000x reference)
//
#include <hip/hip_runtime.h>

#define SQ 2048
#define NB 2
#define NH 16
#define DH 128
#define NT32 64                      // 32-row KV tiles
#define NQT 32                       // 64-row Q tiles
#define SCALE_L2E 0.1275174609f      // (1/sqrt(128)) * log2(e)
#define LOG2E 1.4426950408889634f
#define DEFER_THR 11.0f              // ~8 nats in log2 units

typedef _Float16 f16x8 __attribute__((ext_vector_type(8)));
typedef _Float16 f16x4 __attribute__((ext_vector_type(4)));
typedef float f32x4 __attribute__((ext_vector_type(4)));

static __device__ __forceinline__ _Float16 f2h(float f) { return (_Float16)f; }

// ---------------------------------------------------------------------------
// Pre-pass: K -> fp16 [b][t][32][128] swizzled; V -> fp16 [b][t][128][32]
// (transposed) swizzled. Swizzle ^((row&7)<<3) baked into the GLOBAL layout,
// so hot-loop staging is a pure linear copy (global_load_lds-compatible).
// ---------------------------------------------------------------------------
__global__ __launch_bounds__(256)
void prepack(const float* __restrict__ k, const float* __restrict__ v,
             _Float16* __restrict__ kws, _Float16* __restrict__ vws) {
    const int bid   = blockIdx.x;        // 0..255
    const int which = bid >> 7;          // 0 = K, 1 = V
    const int b     = (bid >> 6) & 1;
    const int t     = bid & 63;
    const int tid   = threadIdx.x;

    if (which == 0) {
        const float* kbase = k + (size_t)t * 32 * (NB * DH) + b * DH;
        _Float16* dst = kws + ((size_t)b * NT32 + t) * 4096;
        #pragma unroll
        for (int p = 0; p < 4; ++p) {
            const int id4 = p * 256 + tid;           // 1024 float4 chunks
            const int row = id4 >> 5;                // 32 f4 per 128-wide row
            const int c0  = (id4 & 31) << 2;
            f32x4 a = *(const f32x4*)(kbase + (size_t)row * (NB * DH) + c0);
            const int e = (row * 128 + c0) ^ ((row & 7) << 3);
            f16x4 pk = { f2h(a.x), f2h(a.y), f2h(a.z), f2h(a.w) };
            *(f16x4*)(dst + e) = pk;
        }
    } else {
        const float* vbase = v + b * DH;
        _Float16* dst = vws + ((size_t)b * NT32 + t) * 4096;
        const int d    = tid & 127;
        const int half = tid >> 7;
        #pragma unroll
        for (int p = 0; p < 4; ++p) {
            const int c0 = (p * 2 + half) * 4;       // kv within tile
            float a0 = vbase[(size_t)(t * 32 + c0 + 0) * (NB * DH) + d];
            float a1 = vbase[(size_t)(t * 32 + c0 + 1) * (NB * DH) + d];
            float a2 = vbase[(size_t)(t * 32 + c0 + 2) * (NB * DH) + d];
            float a3 = vbase[(size_t)(t * 32 + c0 + 3) * (NB * DH) + d];
            const int e = (d * 32 + c0) ^ ((d & 7) << 3);
            f16x4 pk = { f2h(a0), f2h(a1), f2h(a2), f2h(a3) };
            *(f16x4*)(dst + e) = pk;
        }
    }
}

static __device__ __forceinline__ void gload16(const _Float16* gsrc, _Float16* ldst) {
    __builtin_amdgcn_global_load_lds(
        (const __attribute__((address_space(1))) void*)gsrc,
        (__attribute__((address_space(3))) void*)ldst, 16, 0, 0);
}

// ---------------------------------------------------------------------------
// Hot kernel: 4 waves x 16 q-rows (64-row q-tiles), KVBLK=32, 16x16x32 MFMA.
// 36 KB LDS + <=128 VGPR -> 4 blocks/CU, grid 1024 = all blocks resident.
// ---------------------------------------------------------------------------
__global__ __launch_bounds__(256, 4)
void attn_fwd(const float* __restrict__ q, const _Float16* __restrict__ kws,
              const _Float16* __restrict__ vws, const float* __restrict__ sinks,
              float* __restrict__ out) {
    __shared__ _Float16 Kb[2][4096];     // 32x128 swizzled, dbuf
    __shared__ _Float16 Vb[2][4096];     // 128x32 (V^T) swizzled, dbuf
    __shared__ _Float16 Plds[4][512];    // per-wave 16x32

    const int tid  = threadIdx.x;
    const int w    = tid >> 6;
    const int lane = tid & 63;
    const int r    = lane & 15;
    const int g    = lane >> 4;

    const int bid   = blockIdx.x;
    const int bh    = bid & 31;
    const int b     = bh & 1;
    const int h     = bh >> 1;
    const int qtIdx = bid >> 5;          // 0..31
    const int jj    = qtIdx & 7;
    const int mm    = qtIdx >> 3;
    // constant per-CU work under round-robin dispatch: {j,15-j,16+j,31-j}
    const int qt = (mm == 0) ? jj : (mm == 1) ? 15 - jj
                 : (mm == 2) ? 16 + jj : 31 - jj;
    const int q0 = qt * 64;
    const int sq = q0 + w * 16 + r;

    // ---- Q fragments (B-operand), SCALE*log2e folded ----
    f16x8 qf[4];
    {
        const float* qrow = q + ((size_t)sq * NB + b) * (NH * DH) + h * DH;
        #pragma unroll
        for (int kc = 0; kc < 4; ++kc) {
            const int d0 = kc * 32 + g * 8;
            f32x4 a = *(const f32x4*)(qrow + d0);
            f32x4 c = *(const f32x4*)(qrow + d0 + 4);
            f16x8 t;
            t[0] = f2h(a.x * SCALE_L2E); t[1] = f2h(a.y * SCALE_L2E);
            t[2] = f2h(a.z * SCALE_L2E); t[3] = f2h(a.w * SCALE_L2E);
            t[4] = f2h(c.x * SCALE_L2E); t[5] = f2h(c.y * SCALE_L2E);
            t[6] = f2h(c.z * SCALE_L2E); t[7] = f2h(c.w * SCALE_L2E);
            qf[kc] = t;
        }
    }

    float m_run = sinks[h] * LOG2E;      // base-2 logit space
    float l_run = 1.0f;                  // sink contribution
    f32x4 acc[8];
    #pragma unroll
    for (int i = 0; i < 8; ++i) acc[i] = (f32x4)(0.0f);

    const _Float16* ktiles = kws + (size_t)b * NT32 * 4096;
    const _Float16* vtiles = vws + (size_t)b * NT32 * 4096;
    const int ntiles = 2 * qt + 2;
    const int wlimit = q0 + w * 16 + 15;     // wave live while ktb <= wlimit

    // prologue: stage tile 0 into buf0 (2x16B per thread per tensor)
    #pragma unroll
    for (int p = 0; p < 2; ++p) {
        const int off = (p * 256 + tid) * 8;
        gload16(ktiles + off, &Kb[0][off]);
        gload16(vtiles + off, &Vb[0][off]);
    }
    asm volatile("s_waitcnt vmcnt(0)" ::: "memory");
    __builtin_amdgcn_s_barrier();

    for (int it = 0; it < ntiles; ++it) {
        const int cur = it & 1;
        if (it + 1 < ntiles) {
            const _Float16* kn = ktiles + (size_t)(it + 1) * 4096;
            const _Float16* vn = vtiles + (size_t)(it + 1) * 4096;
            #pragma unroll
            for (int p = 0; p < 2; ++p) {
                const int off = (p * 256 + tid) * 8;
                gload16(kn + off, &Kb[cur ^ 1][off]);
                gload16(vn + off, &Vb[cur ^ 1][off]);
            }
        }

        const int ktb = it * 32;
        if (ktb <= wlimit) {
            // ---- S^T = K * Q^T : lane holds S[q=r][kv = ktb+ct*16+g*4+i] ----
            float sv[8];
            #pragma unroll
            for (int ct = 0; ct < 2; ++ct) {
                f32x4 sa = (f32x4)(0.0f);
                const int c = ct * 16 + r;
                #pragma unroll
                for (int kc = 0; kc < 4; ++kc) {
                    const int e = (c * 128 + kc * 32 + g * 8) ^ ((c & 7) << 3);
                    f16x8 kf = *(const f16x8*)(&Kb[cur][e]);
                    sa = __builtin_amdgcn_mfma_f32_16x16x32_f16(kf, qf[kc], sa, 0, 0, 0);
                }
                #pragma unroll
                for (int i = 0; i < 4; ++i) sv[ct * 4 + i] = sa[i];
            }

            // ---- causal mask (wave-uniform guard) ----
            if (ktb + 31 > q0 + w * 16) {
                #pragma unroll
                for (int ct = 0; ct < 2; ++ct)
                    #pragma unroll
                    for (int i = 0; i < 4; ++i) {
                        const int tk = ktb + ct * 16 + g * 4 + i;
                        if (tk > sq) sv[ct * 4 + i] = -1e30f;
                    }
            }

            // ---- online softmax (base-2, tree reductions) ----
            float a0 = fmaxf(sv[0], sv[1]), a1 = fmaxf(sv[2], sv[3]);
            float a2 = fmaxf(sv[4], sv[5]), a3 = fmaxf(sv[6], sv[7]);
            float mx = fmaxf(fmaxf(a0, a1), fmaxf(a2, a3));
            mx = fmaxf(mx, __shfl_xor(mx, 16));
            mx = fmaxf(mx, __shfl_xor(mx, 32));

            if (!__all(mx <= m_run + DEFER_THR)) {   // defer-max (T13)
                const float mnew = fmaxf(m_run, mx);
                const float corr = __builtin_amdgcn_exp2f(m_run - mnew);
                m_run = mnew;
                l_run *= corr;
                #pragma unroll
                for (int i = 0; i < 4; ++i) {
                    const float ci = __shfl(corr, (lane & 48) | (g * 4 + i));
                    #pragma unroll
                    for (int nb = 0; nb < 8; ++nb) acc[nb][i] *= ci;
                }
            }

            #pragma unroll
            for (int i = 0; i < 8; ++i)
                sv[i] = __builtin_amdgcn_exp2f(sv[i] - m_run);
            float s0 = (sv[0] + sv[1]) + (sv[2] + sv[3]);
            float s1 = (sv[4] + sv[5]) + (sv[6] + sv[7]);
            float ls = s0 + s1;
            ls += __shfl_xor(ls, 16);
            ls += __shfl_xor(ls, 32);
            l_run += ls;

            // ---- P -> per-wave LDS (C-layout -> A-layout) ----
            #pragma unroll
            for (int ct = 0; ct < 2; ++ct) {
                f16x4 pb = { f2h(sv[ct * 4 + 0]), f2h(sv[ct * 4 + 1]),
                             f2h(sv[ct * 4 + 2]), f2h(sv[ct * 4 + 3]) };
                const int c0 = ct * 16 + g * 4;
                const int e = (r * 32 + c0) ^ ((r & 7) << 3);
                *(f16x4*)(&Plds[w][e]) = pb;
            }

            // ---- O += P * V ----
            const int ep = (r * 32 + g * 8) ^ ((r & 7) << 3);
            f16x8 pf = *(const f16x8*)(&Plds[w][ep]);
            #pragma unroll
            for (int nb = 0; nb < 8; ++nb) {
                const int d = nb * 16 + r;
                const int ev = (d * 32 + g * 8) ^ ((d & 7) << 3);
                f16x8 vf = *(const f16x8*)(&Vb[cur][ev]);
                acc[nb] = __builtin_amdgcn_mfma_f32_16x16x32_f16(pf, vf, acc[nb], 0, 0, 0);
            }
        }

        asm volatile("s_waitcnt vmcnt(0)" ::: "memory");
        __builtin_amdgcn_s_barrier();
    }

    // ---- epilogue: normalize (stats keyed by q=r, acc rows are g*4+i) ----
    #pragma unroll
    for (int i = 0; i < 4; ++i) {
        const float li = __shfl(l_run, (lane & 48) | (g * 4 + i));
        const float rl = 1.0f / li;
        const int row = q0 + w * 16 + g * 4 + i;
        float* op = out + ((size_t)row * NB + b) * (NH * DH) + h * DH + r;
        #pragma unroll
        for (int nb = 0; nb < 8; ++nb)
            op[nb * 16] = acc[nb][i] * rl;
    }
}

extern "C" void kernel_launch(void* const* d_in, const int* in_sizes, int n_in,
                              void* d_out, int out_size, void* d_ws, size_t ws_size,
                              hipStream_t stream) {
    const float* q     = (const float*)d_in[0];
    const float* k     = (const float*)d_in[1];
    const float* v     = (const float*)d_in[2];
    const float* sinks = (const float*)d_in[3];
    float* out = (float*)d_out;

    _Float16* kws = (_Float16*)d_ws;                        // 1 MB
    _Float16* vws = kws + (size_t)NB * NT32 * 4096;         // 1 MB

    prepack<<<dim3(256), 256, 0, stream>>>(k, v, kws, vws);
    attn_fwd<<<dim3(NQT * NB * NH), 256, 0, stream>>>(q, kws, vws, sinks, out);
}

// Round 7
// 72.599 us; speedup vs baseline: 1.2342x; 1.2342x over previous
//
#include <hip/hip_runtime.h>

#define SQ 2048
#define NB 2
#define NH 16
#define DH 128
#define NKT 32                       // 64-row KV tiles
#define NQT 32                       // 64-row Q tiles
#define SCALE_L2E 0.1275174609f      // (1/sqrt(128)) * log2(e)
#define LOG2E 1.4426950408889634f
#define DEFER_THR 11.0f              // ~8 nats in log2 units

typedef _Float16 f16x8 __attribute__((ext_vector_type(8)));
typedef _Float16 f16x4 __attribute__((ext_vector_type(4)));
typedef float f32x4 __attribute__((ext_vector_type(4)));

static __device__ __forceinline__ _Float16 f2h(float f) { return (_Float16)f; }

// ---------------------------------------------------------------------------
// Pre-pass: K -> fp16 [b][t][64][128] swizzled; V -> fp16 [b][t][128][64]
// (transposed) swizzled. Swizzle baked into GLOBAL layout so hot-loop staging
// is a pure linear copy (global_load_lds-compatible).
// ---------------------------------------------------------------------------
__global__ __launch_bounds__(256)
void prepack(const float* __restrict__ k, const float* __restrict__ v,
             _Float16* __restrict__ kws, _Float16* __restrict__ vws) {
    const int bid   = blockIdx.x;        // 0..127
    const int which = bid >> 6;          // 0 = K, 1 = V
    const int b     = (bid >> 5) & 1;
    const int t     = bid & 31;
    const int tid   = threadIdx.x;

    if (which == 0) {
        const float* kbase = k + (size_t)t * 64 * (NB * DH) + b * DH;
        _Float16* dst = kws + ((size_t)b * NKT + t) * 8192;
        #pragma unroll
        for (int p = 0; p < 8; ++p) {
            const int id4 = p * 256 + tid;           // 2048 float4 chunks
            const int row = id4 >> 5;                // 32 f4 per 128-wide row
            const int c0  = (id4 & 31) << 2;
            f32x4 a = *(const f32x4*)(kbase + (size_t)row * (NB * DH) + c0);
            const int e = (row * 128 + c0) ^ ((row & 7) << 3);
            f16x4 pk = { f2h(a.x), f2h(a.y), f2h(a.z), f2h(a.w) };
            *(f16x4*)(dst + e) = pk;
        }
    } else {
        const float* vbase = v + b * DH;
        _Float16* dst = vws + ((size_t)b * NKT + t) * 8192;
        const int d    = tid & 127;
        const int half = tid >> 7;
        #pragma unroll
        for (int p = 0; p < 8; ++p) {
            const int c0 = (p * 2 + half) * 4;       // kv within tile
            float a0 = vbase[(size_t)(t * 64 + c0 + 0) * (NB * DH) + d];
            float a1 = vbase[(size_t)(t * 64 + c0 + 1) * (NB * DH) + d];
            float a2 = vbase[(size_t)(t * 64 + c0 + 2) * (NB * DH) + d];
            float a3 = vbase[(size_t)(t * 64 + c0 + 3) * (NB * DH) + d];
            const int e = (d * 64 + c0) ^ ((d & 7) << 3);
            f16x4 pk = { f2h(a0), f2h(a1), f2h(a2), f2h(a3) };
            *(f16x4*)(dst + e) = pk;
        }
    }
}

static __device__ __forceinline__ void gload16(const _Float16* gsrc, _Float16* ldst) {
    __builtin_amdgcn_global_load_lds(
        (const __attribute__((address_space(1))) void*)gsrc,
        (__attribute__((address_space(3))) void*)ldst, 16, 0, 0);
}

// One 64-KV-row tile update for one q-context (R3-verified fragment layouts).
static __device__ __forceinline__ void tile_update(
    const _Float16* __restrict__ Kc, const _Float16* __restrict__ Vc,
    _Float16* __restrict__ Pw, const f16x8* __restrict__ qf,
    f32x4* __restrict__ acc, float& m_run, float& l_run,
    int ktb, int sq, int q0w, int r, int g, int lane) {

    // ---- S^T = K * Q^T : lane holds S[q=r][kv = ktb + ct*16 + g*4 + i] ----
    float sv[16];
    #pragma unroll
    for (int ct = 0; ct < 4; ++ct) {
        f32x4 sa = (f32x4)(0.0f);
        const int c = ct * 16 + r;
        #pragma unroll
        for (int kc = 0; kc < 4; ++kc) {
            const int e = (c * 128 + kc * 32 + g * 8) ^ ((c & 7) << 3);
            f16x8 kf = *(const f16x8*)(&Kc[e]);
            sa = __builtin_amdgcn_mfma_f32_16x16x32_f16(kf, qf[kc], sa, 0, 0, 0);
        }
        #pragma unroll
        for (int i = 0; i < 4; ++i) sv[ct * 4 + i] = sa[i];
    }

    // ---- causal mask (wave-uniform guard, diagonal tiles only) ----
    if (ktb + 63 > q0w) {
        #pragma unroll
        for (int ct = 0; ct < 4; ++ct)
            #pragma unroll
            for (int i = 0; i < 4; ++i) {
                const int tk = ktb + ct * 16 + g * 4 + i;
                if (tk > sq) sv[ct * 4 + i] = -1e30f;
            }
    }

    // ---- online softmax (base-2, tree reductions, stats keyed q=r) ----
    float m0 = fmaxf(fmaxf(sv[0], sv[1]), fmaxf(sv[2], sv[3]));
    float m1 = fmaxf(fmaxf(sv[4], sv[5]), fmaxf(sv[6], sv[7]));
    float m2 = fmaxf(fmaxf(sv[8], sv[9]), fmaxf(sv[10], sv[11]));
    float m3 = fmaxf(fmaxf(sv[12], sv[13]), fmaxf(sv[14], sv[15]));
    float mx = fmaxf(fmaxf(m0, m1), fmaxf(m2, m3));
    mx = fmaxf(mx, __shfl_xor(mx, 16));
    mx = fmaxf(mx, __shfl_xor(mx, 32));

    if (!__all(mx <= m_run + DEFER_THR)) {       // defer-max (T13)
        const float mnew = fmaxf(m_run, mx);
        const float corr = __builtin_amdgcn_exp2f(m_run - mnew);
        m_run = mnew;
        l_run *= corr;
        #pragma unroll
        for (int i = 0; i < 4; ++i) {
            const float ci = __shfl(corr, (lane & 48) | (g * 4 + i));
            #pragma unroll
            for (int nb = 0; nb < 8; ++nb) acc[nb][i] *= ci;
        }
    }

    #pragma unroll
    for (int i = 0; i < 16; ++i)
        sv[i] = __builtin_amdgcn_exp2f(sv[i] - m_run);
    float t0 = (sv[0] + sv[1]) + (sv[2] + sv[3]);
    float t1 = (sv[4] + sv[5]) + (sv[6] + sv[7]);
    float t2 = (sv[8] + sv[9]) + (sv[10] + sv[11]);
    float t3 = (sv[12] + sv[13]) + (sv[14] + sv[15]);
    float ls = (t0 + t1) + (t2 + t3);
    ls += __shfl_xor(ls, 16);
    ls += __shfl_xor(ls, 32);
    l_run += ls;

    // ---- P -> per-wave LDS (C-layout -> A-layout) ----
    #pragma unroll
    for (int ct = 0; ct < 4; ++ct) {
        f16x4 pb = { f2h(sv[ct * 4 + 0]), f2h(sv[ct * 4 + 1]),
                     f2h(sv[ct * 4 + 2]), f2h(sv[ct * 4 + 3]) };
        const int c0 = ct * 16 + g * 4;
        const int e = (r * 64 + c0) ^ ((r & 7) << 3);
        *(f16x4*)(&Pw[e]) = pb;
    }

    // ---- O += P * V ----
    #pragma unroll
    for (int cc = 0; cc < 2; ++cc) {
        const int ep = (r * 64 + cc * 32 + g * 8) ^ ((r & 7) << 3);
        f16x8 pf = *(const f16x8*)(&Pw[ep]);
        #pragma unroll
        for (int nb = 0; nb < 8; ++nb) {
            const int d = nb * 16 + r;
            const int ev = (d * 64 + cc * 32 + g * 8) ^ ((d & 7) << 3);
            f16x8 vf = *(const f16x8*)(&Vc[ev]);
            acc[nb] = __builtin_amdgcn_mfma_f32_16x16x32_f16(pf, vf, acc[nb], 0, 0, 0);
        }
    }
}

// ---------------------------------------------------------------------------
// Hot kernel: causal-folded. Each block owns q-tiles {j, 31-j} -> every block
// does exactly 33 tile-updates. 512 blocks = 2/CU (72KB LDS), uniform work.
// ---------------------------------------------------------------------------
__global__ __launch_bounds__(256, 2)
void attn_fwd(const float* __restrict__ q, const _Float16* __restrict__ kws,
              const _Float16* __restrict__ vws, const float* __restrict__ sinks,
              float* __restrict__ out) {
    __shared__ _Float16 Kb[2][8192];     // 64x128 swizzled, dbuf
    __shared__ _Float16 Vb[2][8192];     // 128x64 (V^T) swizzled, dbuf
    __shared__ _Float16 Plds[4][1024];   // per-wave 16x64

    const int tid  = threadIdx.x;
    const int w    = tid >> 6;
    const int lane = tid & 63;
    const int r    = lane & 15;
    const int g    = lane >> 4;

    const int bid = blockIdx.x;
    const int bh  = bid & 31;
    const int b   = bh & 1;
    const int h   = bh >> 1;
    const int j   = bid >> 5;            // 0..15
    const int qtL = j, qtH = NQT - 1 - j;
    const int q0L = qtL * 64, q0H = qtH * 64;
    const int sqL = q0L + w * 16 + r, sqH = q0H + w * 16 + r;

    // ---- Q fragments for both contexts, SCALE*log2e folded ----
    f16x8 qfL[4], qfH[4];
    #pragma unroll
    for (int ctx = 0; ctx < 2; ++ctx) {
        const int sq = ctx ? sqH : sqL;
        f16x8* qf = ctx ? qfH : qfL;
        const float* qrow = q + ((size_t)sq * NB + b) * (NH * DH) + h * DH;
        #pragma unroll
        for (int kc = 0; kc < 4; ++kc) {
            const int d0 = kc * 32 + g * 8;
            f32x4 a = *(const f32x4*)(qrow + d0);
            f32x4 c = *(const f32x4*)(qrow + d0 + 4);
            f16x8 t;
            t[0] = f2h(a.x * SCALE_L2E); t[1] = f2h(a.y * SCALE_L2E);
            t[2] = f2h(a.z * SCALE_L2E); t[3] = f2h(a.w * SCALE_L2E);
            t[4] = f2h(c.x * SCALE_L2E); t[5] = f2h(c.y * SCALE_L2E);
            t[6] = f2h(c.z * SCALE_L2E); t[7] = f2h(c.w * SCALE_L2E);
            qf[kc] = t;
        }
    }

    const float sink2 = sinks[h] * LOG2E;
    float mL = sink2, lL = 1.0f, mH = sink2, lH = 1.0f;
    f32x4 accL[8], accH[8];
    #pragma unroll
    for (int i = 0; i < 8; ++i) { accL[i] = (f32x4)(0.0f); accH[i] = (f32x4)(0.0f); }

    const _Float16* ktiles = kws + (size_t)b * NKT * 8192;
    const _Float16* vtiles = vws + (size_t)b * NKT * 8192;
    const int ntiles = qtH + 1;          // 17..32

    // prologue: stage tile 0 (4x16B per thread per tensor)
    #pragma unroll
    for (int p = 0; p < 4; ++p) {
        const int off = (p * 256 + tid) * 8;
        gload16(ktiles + off, &Kb[0][off]);
        gload16(vtiles + off, &Vb[0][off]);
    }
    asm volatile("s_waitcnt vmcnt(0)" ::: "memory");
    __builtin_amdgcn_s_barrier();

    for (int it = 0; it < ntiles; ++it) {
        const int cur = it & 1;
        if (it + 1 < ntiles) {
            const _Float16* kn = ktiles + (size_t)(it + 1) * 8192;
            const _Float16* vn = vtiles + (size_t)(it + 1) * 8192;
            #pragma unroll
            for (int p = 0; p < 4; ++p) {
                const int off = (p * 256 + tid) * 8;
                gload16(kn + off, &Kb[cur ^ 1][off]);
                gload16(vn + off, &Vb[cur ^ 1][off]);
            }
        }

        const int ktb = it * 64;
        // H context: live for all tiles (up to its diagonal)
        if (ktb <= q0H + w * 16 + 15)
            tile_update(Kb[cur], Vb[cur], Plds[w], qfH, accH, mH, lH,
                        ktb, sqH, q0H + w * 16, r, g, lane);
        // L context: live while it <= qtL
        if (ktb <= q0L + w * 16 + 15)
            tile_update(Kb[cur], Vb[cur], Plds[w], qfL, accL, mL, lL,
                        ktb, sqL, q0L + w * 16, r, g, lane);

        asm volatile("s_waitcnt vmcnt(0)" ::: "memory");
        __builtin_amdgcn_s_barrier();
    }

    // ---- epilogue: normalize + store both contexts ----
    #pragma unroll
    for (int ctx = 0; ctx < 2; ++ctx) {
        const int q0 = ctx ? q0H : q0L;
        const float lr = ctx ? lH : lL;
        const f32x4* acc = ctx ? accH : accL;
        #pragma unroll
        for (int i = 0; i < 4; ++i) {
            const float li = __shfl(lr, (lane & 48) | (g * 4 + i));
            const float rl = 1.0f / li;
            const int row = q0 + w * 16 + g * 4 + i;
            float* op = out + ((size_t)row * NB + b) * (NH * DH) + h * DH + r;
            #pragma unroll
            for (int nb = 0; nb < 8; ++nb)
                op[nb * 16] = acc[nb][i] * rl;
        }
    }
}

extern "C" void kernel_launch(void* const* d_in, const int* in_sizes, int n_in,
                              void* d_out, int out_size, void* d_ws, size_t ws_size,
                              hipStream_t stream) {
    const float* q     = (const float*)d_in[0];
    const float* k     = (const float*)d_in[1];
    const float* v     = (const float*)d_in[2];
    const float* sinks = (const float*)d_in[3];
    float* out = (float*)d_out;

    _Float16* kws = (_Float16*)d_ws;                        // 1 MB
    _Float16* vws = kws + (size_t)NB * NKT * 8192;          // 1 MB

    prepack<<<dim3(128), 256, 0, stream>>>(k, v, kws, vws);
    attn_fwd<<<dim3((NQT / 2) * NB * NH), 256, 0, stream>>>(q, kws, vws, sinks, out);
}